// Round 1
// baseline (576.892 us; speedup 1.0000x reference)
//
#include <hip/hip_runtime.h>

#define IMG_H 4200
#define IMG_W 3200
#define HF 84
#define WF 64
#define NB 8
// feature tiles = 8*84*64 = 43008

typedef const __attribute__((address_space(1))) unsigned int* gl_p;
typedef __attribute__((address_space(3))) unsigned int* lds_p;

__device__ __forceinline__ void gl_lds16(const void* g, void* l) {
    __builtin_amdgcn_global_load_lds((gl_p)g, (lds_p)l, 16, 0, 0);
}

// Kernel 1: 50x50 stride-50 VALID conv, 1 -> 2 channels.
// One block per tile-row (n,i): 64 tiles, lane = tile j, waves split kx (13/13/12/12).
// X rows stream through double-buffered LDS via global_load_lds; weights broadcast from LDS.
__global__ __launch_bounds__(256) void conv1_kernel(
    const float* __restrict__ X, const float* __restrict__ cw,
    const float* __restrict__ cb, float* __restrict__ feats /* [N][HF][WF] float2 */) {
    __shared__ float2 w2[2500];                     // (ch0, ch1) per (ky,kx) - broadcast reads
    __shared__ __align__(16) float4 rowbuf[2][800]; // one image row = 3200 floats, dbuf
    __shared__ float2 part[3][WF];                  // cross-wave partials

    const int tid = threadIdx.x;
    const int wave = tid >> 6;
    const int lane = tid & 63;
    const int b = blockIdx.x;        // [0, 672)
    const int n = b / HF;
    const int i = b - n * HF;

    for (int e = tid; e < 2500; e += 256)
        w2[e] = make_float2(cw[e], cw[2500 + e]);

    const float* Xrow0 = X + ((size_t)n * IMG_H + (size_t)i * 50) * IMG_W;

    // stage row 0 into buf 0 (800 float4, 256 threads: 3 full rounds + 32-thread tail)
    {
        const float4* s = (const float4*)Xrow0;
        gl_lds16(s + tid,       &rowbuf[0][tid]);
        gl_lds16(s + tid + 256, &rowbuf[0][tid + 256]);
        gl_lds16(s + tid + 512, &rowbuf[0][tid + 512]);
        if (tid < 32) gl_lds16(s + tid + 768, &rowbuf[0][tid + 768]);
    }
    __syncthreads();  // compiler drains vmcnt(0) before s_barrier -> row 0 resident

    const int kx0 = wave * 12 + (wave < 2 ? wave : 2);  // 0,13,26,38
    const int len = (wave < 2) ? 13 : 12;
    float acc0 = 0.f, acc1 = 0.f;

    for (int ky = 0; ky < 50; ++ky) {
        const int cur = ky & 1;
        if (ky < 49) {  // prefetch next row into the other buffer
            const float4* s = (const float4*)(Xrow0 + (size_t)(ky + 1) * IMG_W);
            float4* d = rowbuf[cur ^ 1];
            gl_lds16(s + tid,       d + tid);
            gl_lds16(s + tid + 256, d + tid + 256);
            gl_lds16(s + tid + 512, d + tid + 512);
            if (tid < 32) gl_lds16(s + tid + 768, d + tid + 768);
        }
        const float* rowf = (const float*)rowbuf[cur];
        const float2* wrow = &w2[ky * 50];
#pragma unroll
        for (int t = 0; t < 13; ++t) {
            if (t < len) {                       // wave-uniform predicate
                const int kx = kx0 + t;
                const float xv = rowf[lane * 50 + kx];   // stride-50: 4-way bank alias
                const float2 w = wrow[kx];               // uniform -> LDS broadcast
                acc0 = fmaf(xv, w.x, acc0);
                acc1 = fmaf(xv, w.y, acc1);
            }
        }
        __syncthreads();  // row cur consumed; prefetched row landed
    }

    if (wave > 0) part[wave - 1][lane] = make_float2(acc0, acc1);
    __syncthreads();
    if (wave == 0) {
#pragma unroll
        for (int w = 0; w < 3; ++w) {
            acc0 += part[w][lane].x;
            acc1 += part[w][lane].y;
        }
        ((float2*)feats)[(n * HF + i) * WF + lane] =
            make_float2(acc0 + cb[0], acc1 + cb[1]);
    }
}

// Kernel 2: 3x3 SAME convs (36-ch box, 2-ch cls) + softmax + anchors + clip + mask.
// One thread per feature pixel. (unchanged)
__global__ __launch_bounds__(256) void head_kernel(
    const float* __restrict__ feats, const float* __restrict__ bw,
    const float* __restrict__ bb, const float* __restrict__ clw,
    const float* __restrict__ clb, float* __restrict__ out) {
    __shared__ float s_bw[648];  // [36][2][3][3]
    __shared__ float s_bb[36];
    __shared__ float s_cw[36];   // [2][2][3][3]
    __shared__ float s_cb[2];
    const int tid = threadIdx.x;
    for (int e = tid; e < 648; e += 256) s_bw[e] = bw[e];
    if (tid < 36) { s_bb[tid] = bb[tid]; s_cw[tid] = clw[tid]; }
    if (tid < 2) s_cb[tid] = clb[tid];
    __syncthreads();

    const int p = blockIdx.x * 256 + tid;   // [0, 43008)
    const int j = p % WF;
    const int rem = p / WF;
    const int y = rem % HF;
    const int n = rem / HF;

    float f0[3][3], f1[3][3];
#pragma unroll
    for (int dy = 0; dy < 3; ++dy) {
        int yy = y + dy - 1;
#pragma unroll
        for (int dx = 0; dx < 3; ++dx) {
            int xx = j + dx - 1;
            float2 v = make_float2(0.f, 0.f);
            if (yy >= 0 && yy < HF && xx >= 0 && xx < WF)
                v = ((const float2*)feats)[(n * HF + yy) * WF + xx];
            f0[dy][dx] = v.x;
            f1[dy][dx] = v.y;
        }
    }

    // cls conv + softmax over 2 channels (max-subtracted, same as jax.nn.softmax)
    float c0 = s_cb[0], c1 = s_cb[1];
#pragma unroll
    for (int ky = 0; ky < 3; ++ky)
#pragma unroll
        for (int kx = 0; kx < 3; ++kx) {
            int k = ky * 3 + kx;
            c0 = fmaf(f0[ky][kx], s_cw[k], c0);
            c0 = fmaf(f1[ky][kx], s_cw[9 + k], c0);
            c1 = fmaf(f0[ky][kx], s_cw[18 + k], c1);
            c1 = fmaf(f1[ky][kx], s_cw[27 + k], c1);
        }
    float mx = fmaxf(c0, c1);
    float e0 = expf(c0 - mx), e1 = expf(c1 - mx);
    float p1 = e1 / (e0 + e1);
    const float maskf = (p1 > 0.95f) ? 1.f : 0.f;

    const float gx = (j + 0.5f) * 50.f;
    const float gy = (y + 0.5f) * 50.f;
    // anchors: sizes {16,32,64} x ratios {0.5,1,2}; ws = s/sqrt(r), hs = s*sqrt(r)
    const float wsv[9] = {22.627417f, 16.f, 11.3137085f,
                          45.254834f, 32.f, 22.627417f,
                          90.509668f, 64.f, 45.254834f};
    const float hsv[9] = {11.3137085f, 16.f, 22.627417f,
                          22.627417f, 32.f, 45.254834f,
                          45.254834f, 64.f, 90.509668f};

    float4* outp = (float4*)out + (size_t)p * 9;
#pragma unroll
    for (int a = 0; a < 9; ++a) {
        float o[4];
#pragma unroll
        for (int c = 0; c < 4; ++c) {
            const int ch = a * 4 + c;                 // box channel
            const float* w = &s_bw[ch * 18];
            float acc = s_bb[ch];
#pragma unroll
            for (int ky = 0; ky < 3; ++ky)
#pragma unroll
                for (int kx = 0; kx < 3; ++kx) {
                    int k = ky * 3 + kx;
                    acc = fmaf(f0[ky][kx], w[k], acc);
                    acc = fmaf(f1[ky][kx], w[9 + k], acc);
                }
            o[c] = acc;
        }
        const float hw = 0.5f * wsv[a], hh = 0.5f * hsv[a];
        float x1 = fminf(fmaxf(gx - hw + o[0], 0.f), 3200.f);
        float y1 = fminf(fmaxf(gy - hh + o[1], 0.f), 4200.f);
        float x2 = fminf(fmaxf(gx + hw + o[2], 0.f), 3200.f);
        float y2 = fminf(fmaxf(gy + hh + o[3], 0.f), 4200.f);
        outp[a] = make_float4(x1 * maskf, y1 * maskf, x2 * maskf, y2 * maskf);
    }
}

extern "C" void kernel_launch(void* const* d_in, const int* in_sizes, int n_in,
                              void* d_out, int out_size, void* d_ws, size_t ws_size,
                              hipStream_t stream) {
    const float* X   = (const float*)d_in[0];
    const float* cw  = (const float*)d_in[1];
    const float* cb  = (const float*)d_in[2];
    const float* bw  = (const float*)d_in[3];
    const float* bb  = (const float*)d_in[4];
    const float* clw = (const float*)d_in[5];
    const float* clb = (const float*)d_in[6];
    float* out = (float*)d_out;
    float* feats = (float*)d_ws;  // [8][84][64] float2 = 344 KB

    // 672 tile-rows (8 images x 84 rows), one block each
    conv1_kernel<<<672, 256, 0, stream>>>(X, cw, cb, feats);
    // 43008 pixels / 256 = 168 blocks
    head_kernel<<<168, 256, 0, stream>>>(feats, bw, bb, clw, clb, out);
}